// Round 2
// baseline (8435.003 us; speedup 1.0000x reference)
//
#include <hip/hip_runtime.h>

#define NUSERS  50000
#define NNODES  100000
#define NEDGES  3200000
#define DIM     64
#define OSTRIDE 256   // output row stride: (3+1)*64

// ---------------------------------------------------------------------------
// Kernel 1: ego = concat(user_emb, item_emb); also copy into out[:, 0:64]
// ---------------------------------------------------------------------------
__global__ __launch_bounds__(256) void init_ego(const float* __restrict__ ue,
                                                const float* __restrict__ ie,
                                                float* __restrict__ ego,
                                                float* __restrict__ out) {
    int gid = blockIdx.x * 256 + threadIdx.x;   // over NNODES*16 float4 chunks
    if (gid >= NNODES * 16) return;
    int node = gid >> 4, c = gid & 15;
    float4 v = (node < NUSERS)
        ? ((const float4*)ue)[node * 16 + c]
        : ((const float4*)ie)[(size_t)(node - NUSERS) * 16 + c];
    ((float4*)(ego + (size_t)node * DIM))[c] = v;
    ((float4*)(out + (size_t)node * OSTRIDE))[c] = v;
}

// ---------------------------------------------------------------------------
// Kernel 2: scatter  side[rows[e],:] += vals[e] * ego[cols[e],:]
// 16 threads per edge, each handles a float4 chunk of the 64-dim row.
// ---------------------------------------------------------------------------
__global__ __launch_bounds__(256) void scatter_spmm(const int*   __restrict__ rows,
                                                    const int*   __restrict__ cols,
                                                    const float* __restrict__ vals,
                                                    const float* __restrict__ ego,
                                                    float*       __restrict__ side) {
    int gid = blockIdx.x * 256 + threadIdx.x;   // over NEDGES*16
    if (gid >= NEDGES * 16) return;
    int e = gid >> 4, c = gid & 15;
    int r   = rows[e];
    int col = cols[e];
    float v = vals[e];
    const float4 g = *(const float4*)(ego + (size_t)col * DIM + c * 4);
    float* dst = side + (size_t)r * DIM + c * 4;
    atomicAdd(dst + 0, v * g.x);
    atomicAdd(dst + 1, v * g.y);
    atomicAdd(dst + 2, v * g.z);
    atomicAdd(dst + 3, v * g.w);
}

// ---------------------------------------------------------------------------
// Kernel 3: dense transform + leaky relu + L2 normalize.
//   raw      = leaky_relu(side@Wg + bg + (ego*side)@Wb + bb)
//   ego     <- raw                 (next layer input, UN-normalized)
//   out col <- raw / max(||raw||, eps)
// One wave (64 lanes) per node; lane = output dim. Weights staged in LDS.
// ---------------------------------------------------------------------------
__global__ __launch_bounds__(256) void dense_norm(const float* __restrict__ side,
                                                  float*       __restrict__ ego,
                                                  float*       __restrict__ out,
                                                  const float* __restrict__ Wg,
                                                  const float* __restrict__ bg,
                                                  const float* __restrict__ Wb,
                                                  const float* __restrict__ bb,
                                                  int layer) {
    __shared__ float wg[64 * 64];
    __shared__ float wb[64 * 64];
    __shared__ float bsum[64];
    __shared__ float sb[4][64];
    __shared__ float eb[4][64];

    int tid = threadIdx.x;
    for (int i = tid; i < 4096; i += 256) {
        wg[i] = Wg[layer * 4096 + i];
        wb[i] = Wb[layer * 4096 + i];
    }
    if (tid < 64) bsum[tid] = bg[layer * 64 + tid] + bb[layer * 64 + tid];
    __syncthreads();

    int w = tid >> 6, lane = tid & 63;
    int node = blockIdx.x * 4 + w;

    float s = side[(size_t)node * DIM + lane];
    float e = ego[(size_t)node * DIM + lane];
    sb[w][lane] = s;
    eb[w][lane] = e * s;
    __syncthreads();

    float acc = bsum[lane];
    #pragma unroll
    for (int k = 0; k < 64; ++k) {
        acc += sb[w][k] * wg[k * 64 + lane] + eb[w][k] * wb[k * 64 + lane];
    }

    float val = acc >= 0.f ? acc : 0.2f * acc;

    // next-layer ego is the UN-normalized value (reference semantics)
    ego[(size_t)node * DIM + lane] = val;

    // wave-wide sum of squares (64 lanes)
    float ss = val * val;
    #pragma unroll
    for (int m = 1; m < 64; m <<= 1) ss += __shfl_xor(ss, m, 64);
    float nrm = fmaxf(sqrtf(ss), 1e-12f);

    out[(size_t)node * OSTRIDE + (layer + 1) * DIM + lane] = val / nrm;
}

// ---------------------------------------------------------------------------
extern "C" void kernel_launch(void* const* d_in, const int* in_sizes, int n_in,
                              void* d_out, int out_size, void* d_ws, size_t ws_size,
                              hipStream_t stream) {
    const float* ue   = (const float*)d_in[0];
    const float* ie   = (const float*)d_in[1];
    const float* Wg   = (const float*)d_in[2];
    const float* bg   = (const float*)d_in[3];
    const float* Wb   = (const float*)d_in[4];
    const float* bb   = (const float*)d_in[5];
    const int*   rows = (const int*)d_in[6];
    const int*   cols = (const int*)d_in[7];
    const float* vals = (const float*)d_in[8];
    float* out  = (float*)d_out;
    float* side = (float*)d_ws;                      // 100000*64 floats = 25.6 MB
    float* ego  = side + (size_t)NNODES * DIM;       // another 25.6 MB

    init_ego<<<(NNODES * 16 + 255) / 256, 256, 0, stream>>>(ue, ie, ego, out);

    for (int l = 0; l < 3; ++l) {
        hipMemsetAsync(side, 0, (size_t)NNODES * DIM * sizeof(float), stream);
        scatter_spmm<<<(NEDGES * 16 + 255) / 256, 256, 0, stream>>>(rows, cols, vals, ego, side);
        dense_norm<<<NNODES / 4, 256, 0, stream>>>(side, ego, out, Wg, bg, Wb, bb, l);
    }
}

// Round 3
// 2092.118 us; speedup vs baseline: 4.0318x; 4.0318x over previous
//
#include <hip/hip_runtime.h>

#define NUSERS  50000
#define NNODES  100000
#define NEDGES  3200000
#define DIM     64
#define OSTRIDE 256   // output row stride: (3+1)*64

// ---------------------------------------------------------------------------
// Kernel 1: out[:, 0:64] = concat(user_emb, item_emb)   (layer-0 ego, raw)
// ---------------------------------------------------------------------------
__global__ __launch_bounds__(256) void init_ego(const float* __restrict__ ue,
                                                const float* __restrict__ ie,
                                                float* __restrict__ out) {
    int gid = blockIdx.x * 256 + threadIdx.x;   // over NNODES*16 float4 chunks
    if (gid >= NNODES * 16) return;
    int node = gid >> 4, c = gid & 15;
    float4 v = (node < NUSERS)
        ? ((const float4*)ue)[node * 16 + c]
        : ((const float4*)ie)[(size_t)(node - NUSERS) * 16 + c];
    ((float4*)(out + (size_t)node * OSTRIDE))[c] = v;
}

// ---------------------------------------------------------------------------
// CSR build: histogram -> exclusive scan -> counting sort into (col,val) pairs
// ---------------------------------------------------------------------------
__global__ __launch_bounds__(256) void hist_rows(const int* __restrict__ rows,
                                                 int* __restrict__ deg) {
    int e = blockIdx.x * 256 + threadIdx.x;
    if (e < NEDGES) atomicAdd(&deg[rows[e]], 1);
}

__global__ __launch_bounds__(1024) void scan_deg(const int* __restrict__ deg,
                                                 int* __restrict__ row_start,
                                                 int* __restrict__ cursor) {
    __shared__ int wsum[16];
    __shared__ int carry_s;
    int tid = threadIdx.x, lane = tid & 63, w = tid >> 6;
    if (tid == 0) carry_s = 0;
    __syncthreads();
    for (int base = 0; base < NNODES; base += 1024) {
        int i = base + tid;
        int v = (i < NNODES) ? deg[i] : 0;
        int s = v;                       // inclusive wave scan
        #pragma unroll
        for (int d = 1; d < 64; d <<= 1) { int t = __shfl_up(s, d, 64); if (lane >= d) s += t; }
        if (lane == 63) wsum[w] = s;
        __syncthreads();
        if (w == 0) {                    // scan the 16 wave totals
            int x = (lane < 16) ? wsum[lane] : 0;
            #pragma unroll
            for (int d = 1; d < 16; d <<= 1) { int t = __shfl_up(x, d, 64); if (lane >= d) x += t; }
            if (lane < 16) wsum[lane] = x;
        }
        __syncthreads();
        int c = carry_s;
        int excl = c + (w ? wsum[w - 1] : 0) + s - v;
        if (i < NNODES) { row_start[i] = excl; cursor[i] = excl; }
        int total = wsum[15];
        __syncthreads();
        if (tid == 0) carry_s = c + total;
        __syncthreads();
    }
    if (tid == 0) row_start[NNODES] = carry_s;
}

__global__ __launch_bounds__(256) void build_csr(const int* __restrict__ rows,
                                                 const int* __restrict__ cols,
                                                 const float* __restrict__ vals,
                                                 int* __restrict__ cursor,
                                                 int2* __restrict__ cv) {
    int e = blockIdx.x * 256 + threadIdx.x;
    if (e >= NEDGES) return;
    int r = rows[e];
    int j = atomicAdd(&cursor[r], 1);
    cv[j] = make_int2(cols[e], __float_as_int(vals[e]));
}

// ---------------------------------------------------------------------------
// Fused layer: per row r:
//   side = sum_j val_j * ego[col_j]          (gather-SpMM, lane = dim)
//   raw  = leaky_relu(side@Wg + bg + (ego[r]*side)@Wb + bb)
//   out[r, (l+1)*64 + lane] = raw            (normalized later)
// 4 waves/block, 4 rows/wave. Weights staged in LDS once per block.
// ---------------------------------------------------------------------------
__global__ __launch_bounds__(256) void fused_layer(const int*  __restrict__ row_start,
                                                   const int2* __restrict__ cv,
                                                   float*      __restrict__ out,
                                                   const float* __restrict__ Wg,
                                                   const float* __restrict__ bg,
                                                   const float* __restrict__ Wb,
                                                   const float* __restrict__ bb,
                                                   int layer) {
    __shared__ float wg[4096], wb[4096], bsum[64];
    __shared__ float sb[4][64], eb[4][64];

    int tid = threadIdx.x;
    for (int i = tid; i < 4096; i += 256) {
        wg[i] = Wg[layer * 4096 + i];
        wb[i] = Wb[layer * 4096 + i];
    }
    if (tid < 64) bsum[tid] = bg[layer * 64 + tid] + bb[layer * 64 + tid];
    __syncthreads();

    int w = tid >> 6, lane = tid & 63;
    const float* egoin = out + layer * DIM;   // ego_l lives in out column block l

    #pragma unroll
    for (int rr = 0; rr < 4; ++rr) {
        int row = blockIdx.x * 16 + w * 4 + rr;
        int j0 = row_start[row], j1 = row_start[row + 1];
        float acc = 0.f;
        if (j0 < j1) {                        // software-pipelined gather loop
            int2 c0 = cv[j0];
            for (int j = j0 + 1; j < j1; ++j) {
                int2 c1 = cv[j];
                acc += __int_as_float(c0.y) * egoin[(size_t)c0.x * OSTRIDE + lane];
                c0 = c1;
            }
            acc += __int_as_float(c0.y) * egoin[(size_t)c0.x * OSTRIDE + lane];
        }
        float e = egoin[(size_t)row * OSTRIDE + lane];
        sb[w][lane] = acc;
        eb[w][lane] = e * acc;                // same-wave LDS: DS pipe is in-order

        float r2 = bsum[lane];
        #pragma unroll
        for (int k = 0; k < 64; ++k)
            r2 += sb[w][k] * wg[k * 64 + lane] + eb[w][k] * wb[k * 64 + lane];

        float val = r2 >= 0.f ? r2 : 0.2f * r2;
        out[(size_t)row * OSTRIDE + (layer + 1) * DIM + lane] = val;  // RAW
    }
}

// ---------------------------------------------------------------------------
// Final pass: L2-normalize the three layer column blocks (cols 64..255) in place
// ---------------------------------------------------------------------------
__global__ __launch_bounds__(256) void normalize_cols(float* __restrict__ out) {
    int node = blockIdx.x * 4 + (threadIdx.x >> 6);
    int lane = threadIdx.x & 63;
    float* p = out + (size_t)node * OSTRIDE + DIM;
    #pragma unroll
    for (int b = 0; b < 3; ++b) {
        float v = p[b * 64 + lane];
        float ss = v * v;
        #pragma unroll
        for (int m = 1; m < 64; m <<= 1) ss += __shfl_xor(ss, m, 64);
        p[b * 64 + lane] = v / fmaxf(sqrtf(ss), 1e-12f);
    }
}

// ---------------------------------------------------------------------------
extern "C" void kernel_launch(void* const* d_in, const int* in_sizes, int n_in,
                              void* d_out, int out_size, void* d_ws, size_t ws_size,
                              hipStream_t stream) {
    const float* ue   = (const float*)d_in[0];
    const float* ie   = (const float*)d_in[1];
    const float* Wg   = (const float*)d_in[2];
    const float* bg   = (const float*)d_in[3];
    const float* Wb   = (const float*)d_in[4];
    const float* bb   = (const float*)d_in[5];
    const int*   rows = (const int*)d_in[6];
    const int*   cols = (const int*)d_in[7];
    const float* vals = (const float*)d_in[8];
    float* out = (float*)d_out;

    // workspace: deg[N] | row_start[N+1] | cursor[N] | pad | cv[E]  (~27 MB)
    int*  deg       = (int*)d_ws;
    int*  row_start = deg + NNODES;
    int*  cursor    = row_start + NNODES + 1;
    int2* cv        = (int2*)(cursor + NNODES + 1);   // +1 keeps 8B alignment

    init_ego<<<(NNODES * 16 + 255) / 256, 256, 0, stream>>>(ue, ie, out);

    hipMemsetAsync(deg, 0, NNODES * sizeof(int), stream);
    hist_rows<<<(NEDGES + 255) / 256, 256, 0, stream>>>(rows, deg);
    scan_deg<<<1, 1024, 0, stream>>>(deg, row_start, cursor);
    build_csr<<<(NEDGES + 255) / 256, 256, 0, stream>>>(rows, cols, vals, cursor, cv);

    for (int l = 0; l < 3; ++l)
        fused_layer<<<NNODES / 16, 256, 0, stream>>>(row_start, cv, out, Wg, bg, Wb, bb, l);

    normalize_cols<<<NNODES / 4, 256, 0, stream>>>(out);
}

// Round 4
// 991.358 us; speedup vs baseline: 8.5085x; 2.1104x over previous
//
#include <hip/hip_runtime.h>
#include <hip/hip_bf16.h>

#define NUSERS  50000
#define NNODES  100000
#define NEDGES  3200000
#define DIM     64
#define OSTRIDE 256   // output row stride: (3+1)*64

typedef __hip_bfloat16 bf16;

__device__ __forceinline__ float b2f(bf16 x) { return __bfloat162float(x); }

// ---------------------------------------------------------------------------
// Kernel 1: out[:, 0:64] = concat(ue, ie) (fp32)  and egoA = same in bf16
// ---------------------------------------------------------------------------
__global__ __launch_bounds__(256) void init_ego(const float* __restrict__ ue,
                                                const float* __restrict__ ie,
                                                float* __restrict__ out,
                                                bf16*  __restrict__ egoA) {
    int gid = blockIdx.x * 256 + threadIdx.x;   // over NNODES*16 float4 chunks
    if (gid >= NNODES * 16) return;
    int node = gid >> 4, c = gid & 15;
    float4 v = (node < NUSERS)
        ? ((const float4*)ue)[node * 16 + c]
        : ((const float4*)ie)[(size_t)(node - NUSERS) * 16 + c];
    ((float4*)(out + (size_t)node * OSTRIDE))[c] = v;
    bf16* p = egoA + (size_t)node * DIM + c * 4;
    p[0] = __float2bfloat16(v.x);
    p[1] = __float2bfloat16(v.y);
    p[2] = __float2bfloat16(v.z);
    p[3] = __float2bfloat16(v.w);
}

// ---------------------------------------------------------------------------
// CSR build (single aux array `arr`):
//   hist: arr[r] = deg(r)
//   scan: arr[r] = exclusive start(r)          (in place)
//   build: j = atomicAdd(&arr[r],1)  -> after pass arr[r] == end(r) == start(r+1)
//   reader: j0 = r ? arr[r-1] : 0;  j1 = arr[r]
// ---------------------------------------------------------------------------
__global__ __launch_bounds__(256) void hist_rows(const int* __restrict__ rows,
                                                 int* __restrict__ arr) {
    int e = blockIdx.x * 256 + threadIdx.x;
    if (e < NEDGES) atomicAdd(&arr[rows[e]], 1);
}

__global__ __launch_bounds__(1024) void scan_deg(int* __restrict__ arr) {
    __shared__ int wsum[16];
    __shared__ int carry_s;
    int tid = threadIdx.x, lane = tid & 63, w = tid >> 6;
    if (tid == 0) carry_s = 0;
    __syncthreads();
    for (int base = 0; base < NNODES; base += 1024) {
        int i = base + tid;
        int v = (i < NNODES) ? arr[i] : 0;
        int s = v;                       // inclusive wave scan
        #pragma unroll
        for (int d = 1; d < 64; d <<= 1) { int t = __shfl_up(s, d, 64); if (lane >= d) s += t; }
        if (lane == 63) wsum[w] = s;
        __syncthreads();
        if (w == 0) {
            int x = (lane < 16) ? wsum[lane] : 0;
            #pragma unroll
            for (int d = 1; d < 16; d <<= 1) { int t = __shfl_up(x, d, 64); if (lane >= d) x += t; }
            if (lane < 16) wsum[lane] = x;
        }
        __syncthreads();
        int c = carry_s;
        if (i < NNODES) arr[i] = c + (w ? wsum[w - 1] : 0) + s - v;
        int total = wsum[15];
        __syncthreads();
        if (tid == 0) carry_s = c + total;
        __syncthreads();
    }
}

__global__ __launch_bounds__(256) void build_csr(const int* __restrict__ rows,
                                                 const int* __restrict__ cols,
                                                 const float* __restrict__ vals,
                                                 int* __restrict__ arr,
                                                 int* __restrict__ colS,
                                                 bf16* __restrict__ valS) {
    int e = blockIdx.x * 256 + threadIdx.x;
    if (e >= NEDGES) return;
    int r = rows[e];
    int j = atomicAdd(&arr[r], 1);
    colS[j] = cols[e];
    valS[j] = __float2bfloat16(vals[e]);
}

// ---------------------------------------------------------------------------
// Fused layer. 1 wave per row, lane = dim. 8-way unrolled gather (8 loads in
// flight), bf16 compact ego in, bf16 weights in LDS (18.5KB -> 8 blocks/CU).
// ---------------------------------------------------------------------------
__global__ __launch_bounds__(256) void fused_layer(const int*  __restrict__ arr,
                                                   const int*  __restrict__ colS,
                                                   const bf16* __restrict__ valS,
                                                   const bf16* __restrict__ egoIn,
                                                   bf16*       __restrict__ egoOut,
                                                   float*      __restrict__ out,
                                                   const float* __restrict__ Wg,
                                                   const float* __restrict__ bg,
                                                   const float* __restrict__ Wb,
                                                   const float* __restrict__ bb,
                                                   int layer) {
    __shared__ bf16 wg[4096], wb[4096];
    __shared__ float bsum[64];
    __shared__ float sb[4][64], eb[4][64];

    int tid = threadIdx.x;
    for (int i = tid; i < 4096; i += 256) {
        wg[i] = __float2bfloat16(Wg[layer * 4096 + i]);
        wb[i] = __float2bfloat16(Wb[layer * 4096 + i]);
    }
    if (tid < 64) bsum[tid] = bg[layer * 64 + tid] + bb[layer * 64 + tid];
    __syncthreads();

    int w = tid >> 6, lane = tid & 63;
    int row = blockIdx.x * 4 + w;
    int j0 = row ? arr[row - 1] : 0;
    int j1 = arr[row];

    float a0 = 0.f, a1 = 0.f, a2 = 0.f, a3 = 0.f;
    float a4 = 0.f, a5 = 0.f, a6 = 0.f, a7 = 0.f;
    int j = j0;
    for (; j + 8 <= j1; j += 8) {
        int c0 = colS[j + 0], c1 = colS[j + 1], c2 = colS[j + 2], c3 = colS[j + 3];
        int c4 = colS[j + 4], c5 = colS[j + 5], c6 = colS[j + 6], c7 = colS[j + 7];
        float g0 = b2f(egoIn[(size_t)c0 * DIM + lane]);
        float g1 = b2f(egoIn[(size_t)c1 * DIM + lane]);
        float g2 = b2f(egoIn[(size_t)c2 * DIM + lane]);
        float g3 = b2f(egoIn[(size_t)c3 * DIM + lane]);
        float g4 = b2f(egoIn[(size_t)c4 * DIM + lane]);
        float g5 = b2f(egoIn[(size_t)c5 * DIM + lane]);
        float g6 = b2f(egoIn[(size_t)c6 * DIM + lane]);
        float g7 = b2f(egoIn[(size_t)c7 * DIM + lane]);
        a0 += b2f(valS[j + 0]) * g0;
        a1 += b2f(valS[j + 1]) * g1;
        a2 += b2f(valS[j + 2]) * g2;
        a3 += b2f(valS[j + 3]) * g3;
        a4 += b2f(valS[j + 4]) * g4;
        a5 += b2f(valS[j + 5]) * g5;
        a6 += b2f(valS[j + 6]) * g6;
        a7 += b2f(valS[j + 7]) * g7;
    }
    for (; j < j1; ++j)
        a0 += b2f(valS[j]) * b2f(egoIn[(size_t)colS[j] * DIM + lane]);
    float acc = ((a0 + a1) + (a2 + a3)) + ((a4 + a5) + (a6 + a7));

    float e = out[(size_t)row * OSTRIDE + layer * DIM + lane];
    sb[w][lane] = acc;
    eb[w][lane] = e * acc;   // same-wave LDS write->read (proven pattern, R2)

    float r2 = bsum[lane];
    #pragma unroll
    for (int k = 0; k < 64; ++k)
        r2 += sb[w][k] * b2f(wg[k * 64 + lane]) + eb[w][k] * b2f(wb[k * 64 + lane]);

    float val = r2 >= 0.f ? r2 : 0.2f * r2;
    out[(size_t)row * OSTRIDE + (layer + 1) * DIM + lane] = val;   // RAW
    egoOut[(size_t)row * DIM + lane] = __float2bfloat16(val);      // next-layer input
}

// ---------------------------------------------------------------------------
// Final pass: L2-normalize the three layer column blocks (cols 64..255)
// ---------------------------------------------------------------------------
__global__ __launch_bounds__(256) void normalize_cols(float* __restrict__ out) {
    int node = blockIdx.x * 4 + (threadIdx.x >> 6);
    int lane = threadIdx.x & 63;
    float* p = out + (size_t)node * OSTRIDE + DIM;
    #pragma unroll
    for (int b = 0; b < 3; ++b) {
        float v = p[b * 64 + lane];
        float ss = v * v;
        #pragma unroll
        for (int m = 1; m < 64; m <<= 1) ss += __shfl_xor(ss, m, 64);
        p[b * 64 + lane] = v / fmaxf(sqrtf(ss), 1e-12f);
    }
}

// ---------------------------------------------------------------------------
extern "C" void kernel_launch(void* const* d_in, const int* in_sizes, int n_in,
                              void* d_out, int out_size, void* d_ws, size_t ws_size,
                              hipStream_t stream) {
    const float* ue   = (const float*)d_in[0];
    const float* ie   = (const float*)d_in[1];
    const float* Wg   = (const float*)d_in[2];
    const float* bg   = (const float*)d_in[3];
    const float* Wb   = (const float*)d_in[4];
    const float* bb   = (const float*)d_in[5];
    const int*   rows = (const int*)d_in[6];
    const int*   cols = (const int*)d_in[7];
    const float* vals = (const float*)d_in[8];
    float* out = (float*)d_out;

    // ws layout (45.2 MB total):
    //   arr[N] | colS[E] | valS[E] (bf16) | egoA[N*64] (bf16) | egoB[N*64] (bf16)
    int*  arr  = (int*)d_ws;
    int*  colS = arr + NNODES;
    bf16* valS = (bf16*)(colS + NEDGES);
    bf16* egoA = valS + NEDGES;
    bf16* egoB = egoA + (size_t)NNODES * DIM;

    init_ego<<<(NNODES * 16 + 255) / 256, 256, 0, stream>>>(ue, ie, out, egoA);

    hipMemsetAsync(arr, 0, NNODES * sizeof(int), stream);
    hist_rows<<<(NEDGES + 255) / 256, 256, 0, stream>>>(rows, arr);
    scan_deg<<<1, 1024, 0, stream>>>(arr);
    build_csr<<<(NEDGES + 255) / 256, 256, 0, stream>>>(rows, cols, vals, arr, colS, valS);

    bf16* ei = egoA; bf16* eo = egoB;
    for (int l = 0; l < 3; ++l) {
        fused_layer<<<NNODES / 4, 256, 0, stream>>>(arr, colS, valS, ei, eo, out,
                                                    Wg, bg, Wb, bb, l);
        bf16* t = ei; ei = eo; eo = t;
    }

    normalize_cols<<<NNODES / 4, 256, 0, stream>>>(out);
}

// Round 5
// 659.624 us; speedup vs baseline: 12.7876x; 1.5029x over previous
//
#include <hip/hip_runtime.h>
#include <hip/hip_bf16.h>

#define NUSERS  50000
#define NNODES  100000
#define NEDGES  3200000
#define DIM     64
#define OSTRIDE 256   // output row stride: (3+1)*64
#define NBUCK   391   // ceil(NNODES/256) buckets of 256 rows
#define EPB     8192  // edges per block in bucketing kernels
#define NPBLK   391   // ceil(NEDGES/EPB)

typedef __hip_bfloat16 bf16;

__device__ __forceinline__ float b2f(bf16 x) { return __bfloat162float(x); }
__device__ __forceinline__ float us2f(unsigned short u) {
    return __uint_as_float((unsigned)u << 16);
}

// ---------------------------------------------------------------------------
// out[:, 0:64] = concat(ue, ie) (fp32)  and egoA = same in bf16
// ---------------------------------------------------------------------------
__global__ __launch_bounds__(256) void init_ego(const float* __restrict__ ue,
                                                const float* __restrict__ ie,
                                                float* __restrict__ out,
                                                bf16*  __restrict__ egoA) {
    int gid = blockIdx.x * 256 + threadIdx.x;
    if (gid >= NNODES * 16) return;
    int node = gid >> 4, c = gid & 15;
    float4 v = (node < NUSERS)
        ? ((const float4*)ue)[node * 16 + c]
        : ((const float4*)ie)[(size_t)(node - NUSERS) * 16 + c];
    ((float4*)(out + (size_t)node * OSTRIDE))[c] = v;
    bf16* p = egoA + (size_t)node * DIM + c * 4;
    p[0] = __float2bfloat16(v.x);
    p[1] = __float2bfloat16(v.y);
    p[2] = __float2bfloat16(v.z);
    p[3] = __float2bfloat16(v.w);
}

// ---------------------------------------------------------------------------
// Phase 0: bucket sizes (LDS histogram per block, 1 global atomic per bucket)
// ---------------------------------------------------------------------------
__global__ __launch_bounds__(256) void bucket_count(const int* __restrict__ rows,
                                                    int* __restrict__ bcount) {
    __shared__ int lh[NBUCK];
    int tid = threadIdx.x;
    for (int i = tid; i < NBUCK; i += 256) lh[i] = 0;
    __syncthreads();
    int e0 = blockIdx.x * EPB;
    int e1 = min(e0 + EPB, NEDGES);
    for (int e = e0 + tid; e < e1; e += 256)
        atomicAdd(&lh[rows[e] >> 8], 1);
    __syncthreads();
    for (int i = tid; i < NBUCK; i += 256)
        if (lh[i]) atomicAdd(&bcount[i], lh[i]);
}

// ---------------------------------------------------------------------------
// Exclusive scan over NBUCK bucket counts (single block)
// ---------------------------------------------------------------------------
__global__ __launch_bounds__(512) void bucket_scan(const int* __restrict__ bcount,
                                                   int* __restrict__ bbase,
                                                   int* __restrict__ bcursor,
                                                   int* __restrict__ rs) {
    __shared__ int sc[512];
    int tid = threadIdx.x;
    int v = (tid < NBUCK) ? bcount[tid] : 0;
    sc[tid] = v;
    __syncthreads();
    for (int off = 1; off < 512; off <<= 1) {
        int t = (tid >= off) ? sc[tid - off] : 0;
        __syncthreads();
        sc[tid] += t;
        __syncthreads();
    }
    if (tid < NBUCK) {
        int excl = sc[tid] - v;
        bbase[tid] = excl;
        bcursor[tid] = excl;
    }
    if (tid == 0) {
        bbase[NBUCK] = NEDGES;
        rs[NNODES] = NEDGES;
    }
}

// ---------------------------------------------------------------------------
// Phase 1: place edges into their bucket window (contiguous per-bucket bursts)
// tmp[j].x = (localrow << 20) | col,  tmp[j].y = bf16(val) bits
// ---------------------------------------------------------------------------
__global__ __launch_bounds__(256) void bucket_place(const int*   __restrict__ rows,
                                                    const int*   __restrict__ cols,
                                                    const float* __restrict__ vals,
                                                    int*  __restrict__ bcursor,
                                                    int2* __restrict__ tmp) {
    __shared__ int lh[NBUCK];
    int tid = threadIdx.x;
    for (int i = tid; i < NBUCK; i += 256) lh[i] = 0;
    __syncthreads();
    int e0 = blockIdx.x * EPB;
    int e1 = min(e0 + EPB, NEDGES);
    for (int e = e0 + tid; e < e1; e += 256)
        atomicAdd(&lh[rows[e] >> 8], 1);
    __syncthreads();
    for (int i = tid; i < NBUCK; i += 256) {
        int c = lh[i];
        lh[i] = c ? atomicAdd(&bcursor[i], c) : 0;
    }
    __syncthreads();
    for (int e = e0 + tid; e < e1; e += 256) {
        int r = rows[e];
        int p = atomicAdd(&lh[r >> 8], 1);
        unsigned u = __float_as_uint(vals[e]);
        u = (u + 0x7fffu + ((u >> 16) & 1u)) >> 16;   // f32 -> bf16 RNE
        tmp[p] = make_int2(((r & 255) << 20) | cols[e], (int)u);
    }
}

// ---------------------------------------------------------------------------
// Phase 2: one block per bucket. In-block row histogram + scan -> row_start,
// then scatter into final CSR (dest window ~50KB, L2-local, zero amplification)
// ---------------------------------------------------------------------------
__global__ __launch_bounds__(256) void bucket_to_csr(const int*  __restrict__ bbase,
                                                     const int2* __restrict__ tmp,
                                                     int* __restrict__ rs,
                                                     int* __restrict__ colS,
                                                     unsigned short* __restrict__ valS) {
    __shared__ int rcnt[256];
    __shared__ int cur[256];
    int b = blockIdx.x, tid = threadIdx.x;
    int j0 = bbase[b], j1 = bbase[b + 1];
    rcnt[tid] = 0;
    __syncthreads();
    for (int j = j0 + tid; j < j1; j += 256)
        atomicAdd(&rcnt[tmp[j].x >> 20], 1);
    __syncthreads();
    int own = rcnt[tid];
    // inclusive Hillis-Steele scan over 256
    for (int off = 1; off < 256; off <<= 1) {
        int t = (tid >= off) ? rcnt[tid - off] : 0;
        __syncthreads();
        rcnt[tid] += t;
        __syncthreads();
    }
    int start = j0 + rcnt[tid] - own;   // exclusive
    int row = b * 256 + tid;
    if (row < NNODES) rs[row] = start;
    cur[tid] = start;
    __syncthreads();
    for (int j = j0 + tid; j < j1; j += 256) {
        int2 t2 = tmp[j];
        int p = atomicAdd(&cur[t2.x >> 20], 1);
        colS[p] = t2.x & 0xFFFFF;
        valS[p] = (unsigned short)t2.y;
    }
}

// ---------------------------------------------------------------------------
// Fused layer. 1 wave per row, lane = dim. 8-way unrolled gather.
// ---------------------------------------------------------------------------
__global__ __launch_bounds__(256) void fused_layer(const int*  __restrict__ rs,
                                                   const int*  __restrict__ colS,
                                                   const unsigned short* __restrict__ valS,
                                                   const bf16* __restrict__ egoIn,
                                                   bf16*       __restrict__ egoOut,
                                                   float*      __restrict__ out,
                                                   const float* __restrict__ Wg,
                                                   const float* __restrict__ bg,
                                                   const float* __restrict__ Wb,
                                                   const float* __restrict__ bb,
                                                   int layer) {
    __shared__ bf16 wg[4096], wb[4096];
    __shared__ float bsum[64];
    __shared__ float sb[4][64], eb[4][64];

    int tid = threadIdx.x;
    for (int i = tid; i < 4096; i += 256) {
        wg[i] = __float2bfloat16(Wg[layer * 4096 + i]);
        wb[i] = __float2bfloat16(Wb[layer * 4096 + i]);
    }
    if (tid < 64) bsum[tid] = bg[layer * 64 + tid] + bb[layer * 64 + tid];
    __syncthreads();

    int w = tid >> 6, lane = tid & 63;
    int row = blockIdx.x * 4 + w;
    int j0 = rs[row], j1 = rs[row + 1];

    float a0 = 0.f, a1 = 0.f, a2 = 0.f, a3 = 0.f;
    float a4 = 0.f, a5 = 0.f, a6 = 0.f, a7 = 0.f;
    int j = j0;
    for (; j + 8 <= j1; j += 8) {
        int c0 = colS[j + 0], c1 = colS[j + 1], c2 = colS[j + 2], c3 = colS[j + 3];
        int c4 = colS[j + 4], c5 = colS[j + 5], c6 = colS[j + 6], c7 = colS[j + 7];
        float g0 = b2f(egoIn[(size_t)c0 * DIM + lane]);
        float g1 = b2f(egoIn[(size_t)c1 * DIM + lane]);
        float g2 = b2f(egoIn[(size_t)c2 * DIM + lane]);
        float g3 = b2f(egoIn[(size_t)c3 * DIM + lane]);
        float g4 = b2f(egoIn[(size_t)c4 * DIM + lane]);
        float g5 = b2f(egoIn[(size_t)c5 * DIM + lane]);
        float g6 = b2f(egoIn[(size_t)c6 * DIM + lane]);
        float g7 = b2f(egoIn[(size_t)c7 * DIM + lane]);
        a0 += us2f(valS[j + 0]) * g0;
        a1 += us2f(valS[j + 1]) * g1;
        a2 += us2f(valS[j + 2]) * g2;
        a3 += us2f(valS[j + 3]) * g3;
        a4 += us2f(valS[j + 4]) * g4;
        a5 += us2f(valS[j + 5]) * g5;
        a6 += us2f(valS[j + 6]) * g6;
        a7 += us2f(valS[j + 7]) * g7;
    }
    for (; j < j1; ++j)
        a0 += us2f(valS[j]) * b2f(egoIn[(size_t)colS[j] * DIM + lane]);
    float acc = ((a0 + a1) + (a2 + a3)) + ((a4 + a5) + (a6 + a7));

    float e = out[(size_t)row * OSTRIDE + layer * DIM + lane];
    sb[w][lane] = acc;
    eb[w][lane] = e * acc;

    float r2 = bsum[lane];
    #pragma unroll
    for (int k = 0; k < 64; ++k)
        r2 += sb[w][k] * b2f(wg[k * 64 + lane]) + eb[w][k] * b2f(wb[k * 64 + lane]);

    float val = r2 >= 0.f ? r2 : 0.2f * r2;
    out[(size_t)row * OSTRIDE + (layer + 1) * DIM + lane] = val;   // RAW
    egoOut[(size_t)row * DIM + lane] = __float2bfloat16(val);
}

// ---------------------------------------------------------------------------
// L2-normalize the three layer column blocks (cols 64..255)
// ---------------------------------------------------------------------------
__global__ __launch_bounds__(256) void normalize_cols(float* __restrict__ out) {
    int node = blockIdx.x * 4 + (threadIdx.x >> 6);
    int lane = threadIdx.x & 63;
    float* p = out + (size_t)node * OSTRIDE + DIM;
    #pragma unroll
    for (int b = 0; b < 3; ++b) {
        float v = p[b * 64 + lane];
        float ss = v * v;
        #pragma unroll
        for (int m = 1; m < 64; m <<= 1) ss += __shfl_xor(ss, m, 64);
        p[b * 64 + lane] = v / fmaxf(sqrtf(ss), 1e-12f);
    }
}

// ---------------------------------------------------------------------------
extern "C" void kernel_launch(void* const* d_in, const int* in_sizes, int n_in,
                              void* d_out, int out_size, void* d_ws, size_t ws_size,
                              hipStream_t stream) {
    const float* ue   = (const float*)d_in[0];
    const float* ie   = (const float*)d_in[1];
    const float* Wg   = (const float*)d_in[2];
    const float* bg   = (const float*)d_in[3];
    const float* Wb   = (const float*)d_in[4];
    const float* bb   = (const float*)d_in[5];
    const int*   rows = (const int*)d_in[6];
    const int*   cols = (const int*)d_in[7];
    const float* vals = (const float*)d_in[8];
    float* out = (float*)d_out;

    // ws layout (45.2 MB):
    // rs[N+1] | colS[E] | valS[E] u16 | bcount[NB] bbase[NB+1] bcursor[NB] |
    // tmp[E] int2  (aliased after sort by egoA/egoB bf16 ping-pong)
    int* rs   = (int*)d_ws;
    int* colS = rs + NNODES + 1;
    unsigned short* valS = (unsigned short*)(colS + NEDGES);
    int* bcount  = (int*)(valS + NEDGES);
    int* bbase   = bcount + NBUCK;
    int* bcursor = bbase + NBUCK + 1;
    uintptr_t tp = ((uintptr_t)(bcursor + NBUCK) + 15) & ~(uintptr_t)15;
    int2* tmp = (int2*)tp;
    bf16* egoA = (bf16*)tp;                      // reuses tmp region
    bf16* egoB = egoA + (size_t)NNODES * DIM;

    hipMemsetAsync(bcount, 0, NBUCK * sizeof(int), stream);
    bucket_count<<<NPBLK, 256, 0, stream>>>(rows, bcount);
    bucket_scan<<<1, 512, 0, stream>>>(bcount, bbase, bcursor, rs);
    bucket_place<<<NPBLK, 256, 0, stream>>>(rows, cols, vals, bcursor, tmp);
    bucket_to_csr<<<NBUCK, 256, 0, stream>>>(bbase, tmp, rs, colS, valS);

    // init_ego AFTER the sort: egoA aliases tmp
    init_ego<<<(NNODES * 16 + 255) / 256, 256, 0, stream>>>(ue, ie, out, egoA);

    bf16* ei = egoA; bf16* eo = egoB;
    for (int l = 0; l < 3; ++l) {
        fused_layer<<<NNODES / 4, 256, 0, stream>>>(rs, colS, valS, ei, eo, out,
                                                    Wg, bg, Wb, bb, l);
        bf16* t = ei; ei = eo; eo = t;
    }

    normalize_cols<<<NNODES / 4, 256, 0, stream>>>(out);
}

// Round 6
// 534.616 us; speedup vs baseline: 15.7777x; 1.2338x over previous
//
#include <hip/hip_runtime.h>
#include <hip/hip_bf16.h>

#define NUSERS  50000
#define NNODES  100000
#define NEDGES  3200000
#define DIM     64
#define OSTRIDE 256   // output row stride: (3+1)*64
#define NBUCK   391   // ceil(NNODES/256) buckets of 256 rows
#define EPB     8192  // edges per block in bucketing kernels
#define NPBLK   391   // ceil(NEDGES/EPB)

typedef unsigned short u16;
typedef __attribute__((ext_vector_type(8))) short bf16x8;
typedef __attribute__((ext_vector_type(4))) float f32x4;

__device__ __forceinline__ float us2f(u16 u) {
    return __uint_as_float((unsigned)u << 16);
}
__device__ __forceinline__ u16 f2b(float f) {           // f32 -> bf16 RNE bits
    unsigned u = __float_as_uint(f);
    return (u16)((u + 0x7fffu + ((u >> 16) & 1u)) >> 16);
}

// ---------------------------------------------------------------------------
// out[:, 0:64] = concat(ue, ie) (fp32); ego = same in bf16
// ---------------------------------------------------------------------------
__global__ __launch_bounds__(256) void init_ego(const float* __restrict__ ue,
                                                const float* __restrict__ ie,
                                                float* __restrict__ out,
                                                u16*   __restrict__ ego) {
    int gid = blockIdx.x * 256 + threadIdx.x;
    if (gid >= NNODES * 16) return;
    int node = gid >> 4, c = gid & 15;
    float4 v = (node < NUSERS)
        ? ((const float4*)ue)[node * 16 + c]
        : ((const float4*)ie)[(size_t)(node - NUSERS) * 16 + c];
    ((float4*)(out + (size_t)node * OSTRIDE))[c] = v;
    u16* p = ego + (size_t)node * DIM + c * 4;
    p[0] = f2b(v.x); p[1] = f2b(v.y); p[2] = f2b(v.z); p[3] = f2b(v.w);
}

// ---------------------------------------------------------------------------
// Bucketed counting sort (R4, proven): count -> scan -> place -> to_csr
// ---------------------------------------------------------------------------
__global__ __launch_bounds__(256) void bucket_count(const int* __restrict__ rows,
                                                    int* __restrict__ bcount) {
    __shared__ int lh[NBUCK];
    int tid = threadIdx.x;
    for (int i = tid; i < NBUCK; i += 256) lh[i] = 0;
    __syncthreads();
    int e0 = blockIdx.x * EPB, e1 = min(e0 + EPB, NEDGES);
    for (int e = e0 + tid; e < e1; e += 256)
        atomicAdd(&lh[rows[e] >> 8], 1);
    __syncthreads();
    for (int i = tid; i < NBUCK; i += 256)
        if (lh[i]) atomicAdd(&bcount[i], lh[i]);
}

__global__ __launch_bounds__(512) void bucket_scan(const int* __restrict__ bcount,
                                                   int* __restrict__ bbase,
                                                   int* __restrict__ bcursor,
                                                   int* __restrict__ rs) {
    __shared__ int sc[512];
    int tid = threadIdx.x;
    int v = (tid < NBUCK) ? bcount[tid] : 0;
    sc[tid] = v;
    __syncthreads();
    for (int off = 1; off < 512; off <<= 1) {
        int t = (tid >= off) ? sc[tid - off] : 0;
        __syncthreads();
        sc[tid] += t;
        __syncthreads();
    }
    if (tid < NBUCK) {
        int excl = sc[tid] - v;
        bbase[tid] = excl;
        bcursor[tid] = excl;
    }
    if (tid == 0) { bbase[NBUCK] = NEDGES; rs[NNODES] = NEDGES; }
}

__global__ __launch_bounds__(256) void bucket_place(const int*   __restrict__ rows,
                                                    const int*   __restrict__ cols,
                                                    const float* __restrict__ vals,
                                                    int*  __restrict__ bcursor,
                                                    int2* __restrict__ tmp) {
    __shared__ int lh[NBUCK];
    int tid = threadIdx.x;
    for (int i = tid; i < NBUCK; i += 256) lh[i] = 0;
    __syncthreads();
    int e0 = blockIdx.x * EPB, e1 = min(e0 + EPB, NEDGES);
    for (int e = e0 + tid; e < e1; e += 256)
        atomicAdd(&lh[rows[e] >> 8], 1);
    __syncthreads();
    for (int i = tid; i < NBUCK; i += 256) {
        int c = lh[i];
        lh[i] = c ? atomicAdd(&bcursor[i], c) : 0;
    }
    __syncthreads();
    for (int e = e0 + tid; e < e1; e += 256) {
        int r = rows[e];
        int p = atomicAdd(&lh[r >> 8], 1);
        tmp[p] = make_int2(((r & 255) << 20) | cols[e], (int)f2b(vals[e]));
    }
}

__global__ __launch_bounds__(256) void bucket_to_csr(const int*  __restrict__ bbase,
                                                     const int2* __restrict__ tmp,
                                                     int* __restrict__ rs,
                                                     int* __restrict__ colS,
                                                     u16* __restrict__ valS) {
    __shared__ int rcnt[256];
    __shared__ int cur[256];
    int b = blockIdx.x, tid = threadIdx.x;
    int j0 = bbase[b], j1 = bbase[b + 1];
    rcnt[tid] = 0;
    __syncthreads();
    for (int j = j0 + tid; j < j1; j += 256)
        atomicAdd(&rcnt[tmp[j].x >> 20], 1);
    __syncthreads();
    int own = rcnt[tid];
    for (int off = 1; off < 256; off <<= 1) {
        int t = (tid >= off) ? rcnt[tid - off] : 0;
        __syncthreads();
        rcnt[tid] += t;
        __syncthreads();
    }
    int start = j0 + rcnt[tid] - own;
    int row = b * 256 + tid;
    if (row < NNODES) rs[row] = start;
    cur[tid] = start;
    __syncthreads();
    for (int j = j0 + tid; j < j1; j += 256) {
        int2 t2 = tmp[j];
        int p = atomicAdd(&cur[t2.x >> 20], 1);
        colS[p] = t2.x & 0xFFFFF;
        valS[p] = (u16)t2.y;
    }
}

// ---------------------------------------------------------------------------
// Pure gather SpMM: side[row][d] = sum_j val_j * ego[col_j][d]  (bf16 out)
// 1 wave per row, lane = dim, 8 gathers in flight. No LDS -> max occupancy.
// ---------------------------------------------------------------------------
__global__ __launch_bounds__(256) void spmm(const int* __restrict__ rs,
                                            const int* __restrict__ colS,
                                            const u16* __restrict__ valS,
                                            const u16* __restrict__ egoIn,
                                            u16*       __restrict__ side) {
    int tid = threadIdx.x;
    int w = tid >> 6, lane = tid & 63;
    int row = blockIdx.x * 4 + w;
    int j0 = rs[row], j1 = rs[row + 1];

    float a0 = 0.f, a1 = 0.f, a2 = 0.f, a3 = 0.f;
    float a4 = 0.f, a5 = 0.f, a6 = 0.f, a7 = 0.f;
    int j = j0;
    for (; j + 8 <= j1; j += 8) {
        int c0 = colS[j + 0], c1 = colS[j + 1], c2 = colS[j + 2], c3 = colS[j + 3];
        int c4 = colS[j + 4], c5 = colS[j + 5], c6 = colS[j + 6], c7 = colS[j + 7];
        float g0 = us2f(egoIn[(size_t)c0 * DIM + lane]);
        float g1 = us2f(egoIn[(size_t)c1 * DIM + lane]);
        float g2 = us2f(egoIn[(size_t)c2 * DIM + lane]);
        float g3 = us2f(egoIn[(size_t)c3 * DIM + lane]);
        float g4 = us2f(egoIn[(size_t)c4 * DIM + lane]);
        float g5 = us2f(egoIn[(size_t)c5 * DIM + lane]);
        float g6 = us2f(egoIn[(size_t)c6 * DIM + lane]);
        float g7 = us2f(egoIn[(size_t)c7 * DIM + lane]);
        a0 += us2f(valS[j + 0]) * g0;
        a1 += us2f(valS[j + 1]) * g1;
        a2 += us2f(valS[j + 2]) * g2;
        a3 += us2f(valS[j + 3]) * g3;
        a4 += us2f(valS[j + 4]) * g4;
        a5 += us2f(valS[j + 5]) * g5;
        a6 += us2f(valS[j + 6]) * g6;
        a7 += us2f(valS[j + 7]) * g7;
    }
    for (; j < j1; ++j)
        a0 += us2f(valS[j]) * us2f(egoIn[(size_t)colS[j] * DIM + lane]);
    float acc = ((a0 + a1) + (a2 + a3)) + ((a4 + a5) + (a6 + a7));
    side[(size_t)row * DIM + lane] = f2b(acc);
}

// ---------------------------------------------------------------------------
// Dense layer via MFMA: C[N,64] = [side | ego_raw*side] @ [Wg; Wb] + bsum,
// leaky-relu; write raw fp32 to out col (layer+1), bf16 to ego (in place).
// Block = 4 waves x 16 rows. K=128 as 4 steps of mfma_f32_16x16x32_bf16.
// Slot convention k = 32*s + 8*(lane>>4) + e applied to BOTH A and B.
// ---------------------------------------------------------------------------
__global__ __launch_bounds__(256) void dense_mfma(const u16* __restrict__ side,
                                                  float*     __restrict__ out,
                                                  u16*       __restrict__ ego,
                                                  const float* __restrict__ Wg,
                                                  const float* __restrict__ bg,
                                                  const float* __restrict__ Wb,
                                                  const float* __restrict__ bb,
                                                  int layer) {
    __shared__ u16 bfr[8192];     // [s][t][lane][e] fragment-ordered weights
    __shared__ float lbias[64];

    int tid = threadIdx.x;
    for (int idx = tid; idx < 8192; idx += 256) {
        int e = idx & 7, l = (idx >> 3) & 63, t = (idx >> 9) & 3, s = idx >> 11;
        int k = 32 * s + 8 * (l >> 4) + e;
        int n = 16 * t + (l & 15);
        float wv = (k < 64) ? Wg[layer * 4096 + k * 64 + n]
                            : Wb[layer * 4096 + (k - 64) * 64 + n];
        bfr[idx] = f2b(wv);
    }
    if (tid < 64) lbias[tid] = bg[layer * 64 + tid] + bb[layer * 64 + tid];
    __syncthreads();

    int w = tid >> 6, lane = tid & 63;
    int g = lane >> 4, m = lane & 15;
    int rb = blockIdx.x * 64 + w * 16;
    int rowc = min(rb + m, NNODES - 1);

    // A fragments: side halves (k 0..63) and ego*side halves (k 64..127)
    bf16x8 sf0 = *(const bf16x8*)(side + (size_t)rowc * DIM + g * 8);
    bf16x8 sf1 = *(const bf16x8*)(side + (size_t)rowc * DIM + 32 + g * 8);
    const float* erow = out + (size_t)rowc * OSTRIDE + layer * DIM;
    float4 e0a = *(const float4*)(erow + 8 * g);
    float4 e0b = *(const float4*)(erow + 8 * g + 4);
    float4 e1a = *(const float4*)(erow + 32 + 8 * g);
    float4 e1b = *(const float4*)(erow + 32 + 8 * g + 4);
    float ev0[8] = {e0a.x, e0a.y, e0a.z, e0a.w, e0b.x, e0b.y, e0b.z, e0b.w};
    float ev1[8] = {e1a.x, e1a.y, e1a.z, e1a.w, e1b.x, e1b.y, e1b.z, e1b.w};
    bf16x8 pf0, pf1;
    #pragma unroll
    for (int e = 0; e < 8; ++e) {
        pf0[e] = (short)f2b(us2f((u16)sf0[e]) * ev0[e]);
        pf1[e] = (short)f2b(us2f((u16)sf1[e]) * ev1[e]);
    }

    const bf16x8* B = (const bf16x8*)bfr;   // [ (s*4+t)*64 + lane ]
    f32x4 acc[4];
    #pragma unroll
    for (int t = 0; t < 4; ++t) {
        acc[t] = (f32x4){0.f, 0.f, 0.f, 0.f};
        acc[t] = __builtin_amdgcn_mfma_f32_16x16x32_bf16(sf0, B[(0 * 4 + t) * 64 + lane], acc[t], 0, 0, 0);
        acc[t] = __builtin_amdgcn_mfma_f32_16x16x32_bf16(sf1, B[(1 * 4 + t) * 64 + lane], acc[t], 0, 0, 0);
        acc[t] = __builtin_amdgcn_mfma_f32_16x16x32_bf16(pf0, B[(2 * 4 + t) * 64 + lane], acc[t], 0, 0, 0);
        acc[t] = __builtin_amdgcn_mfma_f32_16x16x32_bf16(pf1, B[(3 * 4 + t) * 64 + lane], acc[t], 0, 0, 0);
    }

    // Epilogue: D col = 16t + (lane&15), row = 4*(lane>>4) + r
    #pragma unroll
    for (int t = 0; t < 4; ++t) {
        float bsv = lbias[16 * t + m];
        #pragma unroll
        for (int r = 0; r < 4; ++r) {
            int rw = rb + 4 * g + r;
            if (rw < NNODES) {
                float v = acc[t][r] + bsv;
                v = v >= 0.f ? v : 0.2f * v;
                out[(size_t)rw * OSTRIDE + (layer + 1) * DIM + 16 * t + m] = v;
                ego[(size_t)rw * DIM + 16 * t + m] = f2b(v);
            }
        }
    }
}

// ---------------------------------------------------------------------------
// L2-normalize the three layer column blocks (cols 64..255)
// ---------------------------------------------------------------------------
__global__ __launch_bounds__(256) void normalize_cols(float* __restrict__ out) {
    int node = blockIdx.x * 4 + (threadIdx.x >> 6);
    int lane = threadIdx.x & 63;
    float* p = out + (size_t)node * OSTRIDE + DIM;
    #pragma unroll
    for (int b = 0; b < 3; ++b) {
        float v = p[b * 64 + lane];
        float ss = v * v;
        #pragma unroll
        for (int m = 1; m < 64; m <<= 1) ss += __shfl_xor(ss, m, 64);
        p[b * 64 + lane] = v / fmaxf(sqrtf(ss), 1e-12f);
    }
}

// ---------------------------------------------------------------------------
extern "C" void kernel_launch(void* const* d_in, const int* in_sizes, int n_in,
                              void* d_out, int out_size, void* d_ws, size_t ws_size,
                              hipStream_t stream) {
    const float* ue   = (const float*)d_in[0];
    const float* ie   = (const float*)d_in[1];
    const float* Wg   = (const float*)d_in[2];
    const float* bg   = (const float*)d_in[3];
    const float* Wb   = (const float*)d_in[4];
    const float* bb   = (const float*)d_in[5];
    const int*   rows = (const int*)d_in[6];
    const int*   cols = (const int*)d_in[7];
    const float* vals = (const float*)d_in[8];
    float* out = (float*)d_out;

    // ws (45.2 MB): rs[N+1] | colS[E] | valS[E] u16 | bucket meta |
    // tmp[E] int2  -- aliased after CSR build by ego[N*64] u16 + side[N*64] u16
    int* rs   = (int*)d_ws;
    int* colS = rs + NNODES + 1;
    u16* valS = (u16*)(colS + NEDGES);
    int* bcount  = (int*)(valS + NEDGES);
    int* bbase   = bcount + NBUCK;
    int* bcursor = bbase + NBUCK + 1;
    uintptr_t tp = ((uintptr_t)(bcursor + NBUCK) + 15) & ~(uintptr_t)15;
    int2* tmp = (int2*)tp;
    u16* ego  = (u16*)tp;                       // 12.8 MB
    u16* side = ego + (size_t)NNODES * DIM;     // 12.8 MB

    hipMemsetAsync(bcount, 0, NBUCK * sizeof(int), stream);
    bucket_count<<<NPBLK, 256, 0, stream>>>(rows, bcount);
    bucket_scan<<<1, 512, 0, stream>>>(bcount, bbase, bcursor, rs);
    bucket_place<<<NPBLK, 256, 0, stream>>>(rows, cols, vals, bcursor, tmp);
    bucket_to_csr<<<NBUCK, 256, 0, stream>>>(bbase, tmp, rs, colS, valS);

    // init_ego AFTER the sort: ego aliases tmp
    init_ego<<<(NNODES * 16 + 255) / 256, 256, 0, stream>>>(ue, ie, out, ego);

    for (int l = 0; l < 3; ++l) {
        spmm<<<NNODES / 4, 256, 0, stream>>>(rs, colS, valS, ego, side);
        dense_mfma<<<(NNODES + 63) / 64, 256, 0, stream>>>(side, out, ego,
                                                           Wg, bg, Wb, bb, l);
    }

    normalize_cols<<<NNODES / 4, 256, 0, stream>>>(out);
}